// Round 2
// baseline (1475.361 us; speedup 1.0000x reference)
//
#include <hip/hip_runtime.h>
#include <hip/hip_bf16.h>
#include <stdint.h>

#define CDIM 1024
#define FDIM 4096
#define NEXP 8
#define NTOK 16384
#define MAXROWS 33792   // 32768 pairs + 8*128 max padding
#define MAXT 264        // MAXROWS/128

typedef __attribute__((ext_vector_type(8))) short bf16x8;
typedef __attribute__((ext_vector_type(4))) float f32x4;

__device__ __forceinline__ short f2b(float f) {
  uint32_t u = __float_as_uint(f);
  u += 0x7fffu + ((u >> 16) & 1u);   // RNE
  return (short)(u >> 16);
}

__device__ __forceinline__ void glds16(const void* g, void* l) {
  __builtin_amdgcn_global_load_lds(
      (const __attribute__((address_space(1))) uint32_t*)g,
      (__attribute__((address_space(3))) uint32_t*)l, 16, 0, 0);
}

// ---------- transpose + fp32->bf16 convert (per-expert matrices) ----------
// in: (R x C) fp32, out: (C x R) bf16. gridDim.z = expert.
__global__ __launch_bounds__(256) void trans_cvt(const float* __restrict__ in,
                                                 short* __restrict__ out,
                                                 int R, int C) {
  __shared__ float tile[32][33];
  int e = blockIdx.z;
  in  += (size_t)e * R * C;
  out += (size_t)e * R * C;
  int c0 = blockIdx.x * 32, r0 = blockIdx.y * 32;
  int tx = threadIdx.x, ty = threadIdx.y;  // (32,8)
#pragma unroll
  for (int k = 0; k < 4; k++)
    tile[ty + 8 * k][tx] = in[(size_t)(r0 + ty + 8 * k) * C + c0 + tx];
  __syncthreads();
#pragma unroll
  for (int k = 0; k < 4; k++)
    out[(size_t)(c0 + ty + 8 * k) * R + r0 + tx] = f2b(tile[tx][ty + 8 * k]);
}

// ---------- gate: fp32 logits, top-2, softmax, bf16(x), expert counts ----------
__global__ __launch_bounds__(256) void gate_kernel(
    const float* __restrict__ x, const float* __restrict__ wg,
    short* __restrict__ xb, int* __restrict__ tidx, float* __restrict__ tw,
    int* __restrict__ cnt) {
  __shared__ int hist[NEXP];
  int t = threadIdx.x, wv = t >> 6, l = t & 63;
  if (t < NEXP) hist[t] = 0;
  __syncthreads();
  int tok = blockIdx.x * 4 + wv;
  const float* xr = x + (size_t)tok * CDIM;
  float acc[8] = {0.f, 0.f, 0.f, 0.f, 0.f, 0.f, 0.f, 0.f};
#pragma unroll
  for (int i = 0; i < CDIM / 64; i++) {
    int c = i * 64 + l;
    float xv = xr[c];
    xb[(size_t)tok * CDIM + c] = f2b(xv);
    const float4* wr = (const float4*)(wg + (size_t)c * NEXP);
    float4 w0 = wr[0], w1 = wr[1];
    acc[0] += xv * w0.x; acc[1] += xv * w0.y;
    acc[2] += xv * w0.z; acc[3] += xv * w0.w;
    acc[4] += xv * w1.x; acc[5] += xv * w1.y;
    acc[6] += xv * w1.z; acc[7] += xv * w1.w;
  }
#pragma unroll
  for (int e2 = 0; e2 < 8; e2++) {
    float v = acc[e2];
#pragma unroll
    for (int s = 32; s > 0; s >>= 1) v += __shfl_xor(v, s, 64);
    acc[e2] = v;
  }
  if (l == 0) {
    float b0 = -1e30f, b1 = -1e30f;
    int i0 = 0, i1 = 0;
#pragma unroll
    for (int e2 = 0; e2 < 8; e2++) {
      float v = acc[e2];
      if (v > b0) { b1 = b0; i1 = i0; b0 = v; i0 = e2; }
      else if (v > b1) { b1 = v; i1 = e2; }
    }
    float w0 = 1.f / (1.f + expf(b1 - b0));  // softmax over {b0,b1}
    tidx[tok * 2] = i0; tidx[tok * 2 + 1] = i1;
    tw[tok * 2] = w0;   tw[tok * 2 + 1] = 1.f - w0;
    atomicAdd(&hist[i0], 1); atomicAdd(&hist[i1], 1);
  }
  __syncthreads();
  if (t < NEXP && hist[t] > 0) atomicAdd(&cnt[t], hist[t]);
}

// meta layout (ints): [0..8) cnt  [8..16) fill  [16..25) padstart
//                     [25] ntiles [26..26+MAXT) tile_e [290..290+MAXT) tile_base
__global__ void schedule_kernel(int* __restrict__ meta, int* __restrict__ perm,
                                float* __restrict__ pw) {
  __shared__ int s_ps[9], s_cnt[8], s_ts[9];
  int t = threadIdx.x;
  if (t == 0) {
    int ps = 0;
    for (int e = 0; e < 8; e++) {
      int c = meta[e];
      s_cnt[e] = c;
      s_ps[e] = ps; s_ts[e] = ps >> 7;
      ps += ((c + 127) >> 7) << 7;
    }
    s_ps[8] = ps; s_ts[8] = ps >> 7;
    meta[25] = ps >> 7;
    for (int e = 0; e < 9; e++) meta[16 + e] = s_ps[e];
  }
  __syncthreads();
  int ntiles = s_ts[8];
  for (int i = t; i < ntiles; i += 256) {
    int e = 0;
    while (i >= s_ts[e + 1]) e++;
    meta[26 + i] = e;
    meta[290 + i] = s_ps[e] + ((i - s_ts[e]) << 7);
  }
  int totrows = s_ps[8];
  for (int pr = t; pr < totrows; pr += 256) {
    int e = 0;
    while (pr >= s_ps[e + 1]) e++;
    if (pr - s_ps[e] >= s_cnt[e]) { perm[pr] = -1; pw[pr] = 0.f; }
  }
}

__global__ __launch_bounds__(256) void fill_kernel(
    const int* __restrict__ tidx, const float* __restrict__ tw,
    int* __restrict__ meta, int* __restrict__ perm, float* __restrict__ pw) {
  int t = blockIdx.x * 256 + threadIdx.x;
#pragma unroll
  for (int k = 0; k < 2; k++) {
    int e = tidx[t * 2 + k];
    int pos = atomicAdd(&meta[8 + e], 1);
    int pr = meta[16 + e] + pos;
    perm[pr] = t;
    pw[pr] = tw[t * 2 + k];
  }
}

// ---------- GEMM1: h_local = gelu( gather(x) @ W1[e] ), bf16 out ----------
// h is indexed by LOCAL tile id (blockIdx.y) so only the current chunk's
// rows exist in the workspace.
__global__ __launch_bounds__(256) void gemm1_kernel(
    const short* __restrict__ xb, const short* __restrict__ w1t,
    short* __restrict__ h, const int* __restrict__ meta,
    const int* __restrict__ perm, int mtbase) {
  __shared__ short As[4096];  // [128 rows][32 k]
  __shared__ short Bs[4096];  // [128 n]  [32 k]  (W1T is n-major, k contiguous)
  int mt = mtbase + blockIdx.y;
  if (mt >= meta[25]) return;
  int e = meta[26 + mt];
  int prbase = meta[290 + mt];
  int n0 = blockIdx.x * 128;
  int t = threadIdx.x, wv = t >> 6, l = t & 63;
  int r = t >> 2, cb = (t & 3) * 8;

  int tok0 = perm[prbase + r];
  int tok1 = perm[prbase + r + 64];
  if (tok0 < 0) tok0 = 0;
  if (tok1 < 0) tok1 = 0;
  const short* a0 = xb + (size_t)tok0 * CDIM + cb;
  const short* a1 = xb + (size_t)tok1 * CDIM + cb;
  const short* bsrc = w1t + (size_t)e * FDIM * CDIM;
  const short* b0 = bsrc + (size_t)(n0 + r) * CDIM + cb;
  const short* b1 = bsrc + (size_t)(n0 + r + 64) * CDIM + cb;

  short* ldsA0 = As + wv * 512;          // bytes [wv*1024)
  short* ldsA1 = As + 2048 + wv * 512;
  short* ldsB0 = Bs + wv * 512;
  short* ldsB1 = Bs + 2048 + wv * 512;

  int wm = wv >> 1, wn = wv & 1;
  int lr = l & 15, lq = l >> 4;
  const short* ap = As + (wm * 64 + lr) * 32 + lq * 8;
  const short* bp = Bs + (wn * 64 + lr) * 32 + lq * 8;

  f32x4 acc[4][4];
#pragma unroll
  for (int i = 0; i < 4; i++)
#pragma unroll
    for (int j = 0; j < 4; j++) acc[i][j] = (f32x4){0.f, 0.f, 0.f, 0.f};

  for (int kt = 0; kt < CDIM / 32; kt++) {
    glds16(a0 + kt * 32, ldsA0);
    glds16(a1 + kt * 32, ldsA1);
    glds16(b0 + kt * 32, ldsB0);
    glds16(b1 + kt * 32, ldsB1);
    __syncthreads();
    bf16x8 af[4], bfr[4];
#pragma unroll
    for (int i = 0; i < 4; i++) af[i] = *(const bf16x8*)(ap + i * 512);
#pragma unroll
    for (int j = 0; j < 4; j++) bfr[j] = *(const bf16x8*)(bp + j * 512);
#pragma unroll
    for (int i = 0; i < 4; i++)
#pragma unroll
      for (int j = 0; j < 4; j++)
        acc[i][j] = __builtin_amdgcn_mfma_f32_16x16x32_bf16(af[i], bfr[j],
                                                            acc[i][j], 0, 0, 0);
    __syncthreads();
  }
  size_t hbase = (size_t)blockIdx.y * 128 * FDIM;
#pragma unroll
  for (int i = 0; i < 4; i++) {
    int row = wm * 64 + i * 16 + lq * 4;
#pragma unroll
    for (int j = 0; j < 4; j++) {
      int col = n0 + wn * 64 + j * 16 + lr;
#pragma unroll
      for (int rr = 0; rr < 4; rr++) {
        float v = acc[i][j][rr];
        float g = 0.5f * v * (1.f + erff(v * 0.70710678118f));
        h[hbase + (size_t)(row + rr) * FDIM + col] = f2b(g);
      }
    }
  }
}

// ---------- GEMM2: out[tok] += w * ( h_local @ W2[e] ) ----------
__global__ __launch_bounds__(256) void gemm2_kernel(
    const short* __restrict__ h, const short* __restrict__ w2t,
    float* __restrict__ out, const int* __restrict__ meta,
    const int* __restrict__ perm, const float* __restrict__ pw, int mtbase) {
  __shared__ short As[4096];
  __shared__ short Bs[4096];
  int mt = mtbase + blockIdx.y;
  if (mt >= meta[25]) return;
  int e = meta[26 + mt];
  int prbase = meta[290 + mt];
  int n0 = blockIdx.x * 128;
  int t = threadIdx.x, wv = t >> 6, l = t & 63;
  int r = t >> 2, cb = (t & 3) * 8;

  size_t hbase = (size_t)blockIdx.y * 128 * FDIM;
  const short* a0 = h + hbase + (size_t)r * FDIM + cb;
  const short* a1 = h + hbase + (size_t)(r + 64) * FDIM + cb;
  const short* bsrc = w2t + (size_t)e * CDIM * FDIM;
  const short* b0 = bsrc + (size_t)(n0 + r) * FDIM + cb;
  const short* b1 = bsrc + (size_t)(n0 + r + 64) * FDIM + cb;

  short* ldsA0 = As + wv * 512;
  short* ldsA1 = As + 2048 + wv * 512;
  short* ldsB0 = Bs + wv * 512;
  short* ldsB1 = Bs + 2048 + wv * 512;

  int wm = wv >> 1, wn = wv & 1;
  int lr = l & 15, lq = l >> 4;
  const short* ap = As + (wm * 64 + lr) * 32 + lq * 8;
  const short* bp = Bs + (wn * 64 + lr) * 32 + lq * 8;

  f32x4 acc[4][4];
#pragma unroll
  for (int i = 0; i < 4; i++)
#pragma unroll
    for (int j = 0; j < 4; j++) acc[i][j] = (f32x4){0.f, 0.f, 0.f, 0.f};

  for (int kt = 0; kt < FDIM / 32; kt++) {
    glds16(a0 + kt * 32, ldsA0);
    glds16(a1 + kt * 32, ldsA1);
    glds16(b0 + kt * 32, ldsB0);
    glds16(b1 + kt * 32, ldsB1);
    __syncthreads();
    bf16x8 af[4], bfr[4];
#pragma unroll
    for (int i = 0; i < 4; i++) af[i] = *(const bf16x8*)(ap + i * 512);
#pragma unroll
    for (int j = 0; j < 4; j++) bfr[j] = *(const bf16x8*)(bp + j * 512);
#pragma unroll
    for (int i = 0; i < 4; i++)
#pragma unroll
      for (int j = 0; j < 4; j++)
        acc[i][j] = __builtin_amdgcn_mfma_f32_16x16x32_bf16(af[i], bfr[j],
                                                            acc[i][j], 0, 0, 0);
    __syncthreads();
  }
#pragma unroll
  for (int i = 0; i < 4; i++) {
#pragma unroll
    for (int rr = 0; rr < 4; rr++) {
      int pr = prbase + wm * 64 + i * 16 + lq * 4 + rr;
      int tok = perm[pr];
      if (tok < 0) continue;
      float w = pw[pr];
#pragma unroll
      for (int j = 0; j < 4; j++) {
        int col = n0 + wn * 64 + j * 16 + lr;
        atomicAdd(&out[(size_t)tok * CDIM + col], acc[i][j][rr] * w);
      }
    }
  }
}

extern "C" void kernel_launch(void* const* d_in, const int* in_sizes, int n_in,
                              void* d_out, int out_size, void* d_ws, size_t ws_size,
                              hipStream_t stream) {
  const float* x  = (const float*)d_in[0];
  const float* wg = (const float*)d_in[1];
  const float* w1 = (const float*)d_in[2];
  const float* w2 = (const float*)d_in[3];
  float* out = (float*)d_out;
  char* ws = (char*)d_ws;

  // ---- fixed workspace layout (~161.4 MB) ----
  size_t off = 0;
  short* xb   = (short*)(ws + off); off += (size_t)NTOK * CDIM * 2;        // 32 MB
  short* w1t  = (short*)(ws + off); off += (size_t)NEXP * FDIM * CDIM * 2; // 64 MB
  short* w2t  = (short*)(ws + off); off += (size_t)NEXP * CDIM * FDIM * 2; // 64 MB
  int*   perm = (int*)  (ws + off); off += (size_t)MAXROWS * 4;
  float* pw   = (float*)(ws + off); off += (size_t)MAXROWS * 4;
  int*   tidx = (int*)  (ws + off); off += (size_t)NTOK * 2 * 4;
  float* tw   = (float*)(ws + off); off += (size_t)NTOK * 2 * 4;
  int*   meta = (int*)  (ws + off); off += 4096;
  off = (off + 255) & ~(size_t)255;
  short* h    = (short*)(ws + off);  // chunk-sized, fills the remainder

  // pick largest tiles-per-chunk whose h buffer fits the remaining ws
  size_t remain = (ws_size > off) ? (ws_size - off) : 0;
  const int tpc_opts[6] = {MAXT, 128, 64, 32, 16, 8};
  int tpc = 8;
  for (int i = 0; i < 6; i++) {
    if ((size_t)tpc_opts[i] * 128 * FDIM * 2 <= remain) { tpc = tpc_opts[i]; break; }
  }
  int nchunks = (MAXT + tpc - 1) / tpc;

  hipMemsetAsync(meta, 0, 64, stream);  // cnt[8] + fill[8]
  hipMemsetAsync(d_out, 0, (size_t)NTOK * CDIM * sizeof(float), stream);

  hipLaunchKernelGGL(trans_cvt, dim3(FDIM / 32, CDIM / 32, NEXP), dim3(32, 8),
                     0, stream, w1, w1t, CDIM, FDIM);
  hipLaunchKernelGGL(trans_cvt, dim3(CDIM / 32, FDIM / 32, NEXP), dim3(32, 8),
                     0, stream, w2, w2t, FDIM, CDIM);
  hipLaunchKernelGGL(gate_kernel, dim3(NTOK / 4), dim3(256), 0, stream,
                     x, wg, xb, tidx, tw, meta);
  hipLaunchKernelGGL(schedule_kernel, dim3(1), dim3(256), 0, stream,
                     meta, perm, pw);
  hipLaunchKernelGGL(fill_kernel, dim3(NTOK / 256), dim3(256), 0, stream,
                     tidx, tw, meta, perm, pw);
  for (int ci = 0; ci < nchunks; ci++) {
    int mtbase = ci * tpc;
    hipLaunchKernelGGL(gemm1_kernel, dim3(FDIM / 128, tpc), dim3(256), 0,
                       stream, xb, w1t, h, meta, perm, mtbase);
    hipLaunchKernelGGL(gemm2_kernel, dim3(CDIM / 128, tpc), dim3(256), 0,
                       stream, h, w2t, out, meta, perm, pw, mtbase);
  }
}